// Round 1
// baseline (240.564 us; speedup 1.0000x reference)
//
#include <hip/hip_runtime.h>
#include <hip/hip_bf16.h>
#include <math.h>

// AdAct: out = piecewise-linear table activation of x, faithfully reproducing
// the reference's bin math (ceil(x/delta)-1, lower-clamped m1, upper-clamp +
// negative-wrap m2, denom==0 -> 1 guard, then x<r / x>s overrides).
//
// Key transform: per bin b = ceil(x/delta)-1 - bmin (b in [0,H-1] for x in
// [r,s]), interp(x) = A[b] + B[b]*x with
//   B = (a2-a1)/denom,  A = (a1*ns2 - a2*ns1)/denom
// using the SAME table values / denom the reference uses, so the only
// deviation is product-rounding reordering (<= ~3e-4 abs, threshold 5.6e-2).
// Bin selection uses IEEE divide + ceilf -> bit-identical to numpy.

__global__ __launch_bounds__(256) void adact_kernel(
    const float* __restrict__ x,
    const float* __restrict__ ns,
    const float* __restrict__ a,
    float* __restrict__ out,
    int n, int H)
{
    extern __shared__ float smem[];
    float*  s_ns  = smem;                      // H floats
    float*  s_a   = smem + H;                  // H floats
    float2* s_tab = (float2*)(smem + 2 * H);   // H float2 (A,B), 8B-aligned

    // Stage ns, a (coalesced).
    for (int i = threadIdx.x; i < H; i += blockDim.x) {
        s_ns[i] = ns[i];
        s_a[i]  = a[i];
    }
    __syncthreads();

    const float r       = s_ns[0];
    const float s       = s_ns[H - 1];
    const float delta   = s_ns[1] - s_ns[0];
    const float a_first = s_a[0];
    const float a_last  = s_a[H - 1];
    // Same fl(r/delta) + ceilf the per-element path uses -> consistent b=0.
    const int bmin = (int)ceilf(r / delta) - 1;

    // Build affine table: replicate reference index math per bin.
    for (int b = threadIdx.x; b < H; b += blockDim.x) {
        int m1_raw = bmin + b;
        int m1 = m1_raw;
        if (m1 < 0) m1 = 0;                 // reference lower clamp
        if (m1 > H - 1) m1 = H - 1;         // safety (jnp OOB clamp)
        int m2 = m1_raw + 1;
        if (m2 >= H) m2 = H - 1;            // reference upper clamp
        if (m2 < 0)  m2 += H;               // reference negative wrap
        if (m2 < 0)  m2 = 0;                // safety
        if (m2 > H - 1) m2 = H - 1;         // safety
        float ns1 = s_ns[m1], ns2 = s_ns[m2];
        float a1  = s_a[m1],  a2  = s_a[m2];
        float denom = ns2 - ns1;
        if (denom == 0.0f) denom = 1.0f;    // reference guard (A=B=0 -> interp=0, exact)
        float Bc = (a2 - a1) / denom;
        float Ac = (a1 * ns2 - a2 * ns1) / denom;
        s_tab[b] = make_float2(Ac, Bc);
    }
    __syncthreads();

    auto eval = [&](float xv) -> float {
        float t = xv / delta;               // IEEE divide: bin must match np exactly
        int b = (int)ceilf(t) - 1 - bmin;
        b = b < 0 ? 0 : (b > H - 1 ? H - 1 : b);  // never triggers for x in [r,s]
        float2 c = s_tab[b];
        float o = fmaf(c.y, xv, c.x);
        if (xv < r) o = a_first;
        if (xv > s) o = a_last;             // x>s wins (outer where), matches order
        return o;
    };

    const int gtid   = blockIdx.x * blockDim.x + threadIdx.x;
    const int stride = gridDim.x * blockDim.x;
    const int n4     = n >> 2;
    const float4* __restrict__ x4 = (const float4*)x;
    float4* __restrict__ o4       = (float4*)out;
    for (int i = gtid; i < n4; i += stride) {
        float4 xv = x4[i];
        float4 ov;
        ov.x = eval(xv.x);
        ov.y = eval(xv.y);
        ov.z = eval(xv.z);
        ov.w = eval(xv.w);
        o4[i] = ov;
    }
    // Tail (n % 4 elements).
    const int rem = n & 3;
    if (gtid < rem) {
        int i = (n4 << 2) + gtid;
        out[i] = eval(x[i]);
    }
}

extern "C" void kernel_launch(void* const* d_in, const int* in_sizes, int n_in,
                              void* d_out, int out_size, void* d_ws, size_t ws_size,
                              hipStream_t stream) {
    const float* x  = (const float*)d_in[0];
    const float* ns = (const float*)d_in[1];
    const float* a  = (const float*)d_in[2];
    float* out = (float*)d_out;
    const int n = in_sizes[0];
    const int H = in_sizes[1];

    int n4 = n >> 2;
    int grid = (n4 + 255) / 256;
    if (grid > 4096) grid = 4096;   // grid-stride: ~8 float4 iters/thread at 32M elems
    if (grid < 1) grid = 1;
    size_t shmem = (size_t)H * 16;  // ns + a + float2 table
    adact_kernel<<<grid, 256, shmem, stream>>>(x, ns, a, out, n, H);
}

// Round 3
// 236.110 us; speedup vs baseline: 1.0189x; 1.0189x over previous
//
#include <hip/hip_runtime.h>
#include <hip/hip_bf16.h>
#include <math.h>

// AdAct piecewise-linear activation. R1 83us @ 2.4TB/s was latency-bound
// (1 load in flight/wave + dependent IEEE-div chain). R2/R3 changes:
//  - UNROLL=8 independent float4 loads issued before any compute (MLP)
//  - x*(1/delta) instead of x/delta: bin flips only at segment boundaries
//    where the interp is continuous -> error ~1e-6, kills the div sequence
//  - nontemporal stores (out never re-read; keep L3 for x)
//    (R3: use clang ext_vector float4 — __builtin_nontemporal_store rejects
//     HIP_vector_type)
// Affine-table transform unchanged: interp = A[b] + B[b]*x, table in LDS.

#define BLOCK 256
#define UNROLL 8

typedef float vfloat4 __attribute__((ext_vector_type(4)));

__global__ __launch_bounds__(BLOCK) void adact_kernel(
    const float* __restrict__ x,
    const float* __restrict__ ns,
    const float* __restrict__ a,
    float* __restrict__ out,
    int n, int H)
{
    extern __shared__ float smem[];
    float*  s_ns  = smem;                      // H floats
    float*  s_a   = smem + H;                  // H floats
    float2* s_tab = (float2*)(smem + 2 * H);   // H float2 (A,B)

    for (int i = threadIdx.x; i < H; i += BLOCK) {
        s_ns[i] = ns[i];
        s_a[i]  = a[i];
    }
    __syncthreads();

    const float r       = s_ns[0];
    const float s       = s_ns[H - 1];
    const float delta   = s_ns[1] - s_ns[0];
    const float rd      = 1.0f / delta;        // recip-mult bin select (see header)
    const float a_first = s_a[0];
    const float a_last  = s_a[H - 1];
    const int bmin = (int)ceilf(r * rd) - 1;   // same formula as per-element path

    // Build affine table, replicating reference index math per bin.
    for (int b = threadIdx.x; b < H; b += BLOCK) {
        int m1_raw = bmin + b;
        int m1 = m1_raw;
        if (m1 < 0) m1 = 0;
        if (m1 > H - 1) m1 = H - 1;
        int m2 = m1_raw + 1;
        if (m2 >= H) m2 = H - 1;
        if (m2 < 0)  m2 += H;
        if (m2 < 0)  m2 = 0;
        if (m2 > H - 1) m2 = H - 1;
        float ns1 = s_ns[m1], ns2 = s_ns[m2];
        float a1  = s_a[m1],  a2  = s_a[m2];
        float denom = ns2 - ns1;
        if (denom == 0.0f) denom = 1.0f;       // -> A=B=0, interp=0 exactly (matches ref)
        float Bc = (a2 - a1) / denom;
        float Ac = (a1 * ns2 - a2 * ns1) / denom;
        s_tab[b] = make_float2(Ac, Bc);
    }
    __syncthreads();

    auto eval = [&](float xv) -> float {
        int b = (int)ceilf(xv * rd) - 1 - bmin;
        b = b < 0 ? 0 : (b > H - 1 ? H - 1 : b);
        float2 c = s_tab[b];
        float o = fmaf(c.y, xv, c.x);
        if (xv < r) o = a_first;
        if (xv > s) o = a_last;
        return o;
    };

    const int n4  = n >> 2;
    const int tid = threadIdx.x;
    const int chunk = BLOCK * UNROLL;          // float4s per block-chunk
    const vfloat4* __restrict__ x4 = (const vfloat4*)x;
    vfloat4* __restrict__ o4       = (vfloat4*)out;

    for (int base = blockIdx.x * chunk; base < n4; base += gridDim.x * chunk) {
        if (base + chunk <= n4) {
            // Full chunk: 8 independent loads in flight before any compute.
            vfloat4 v[UNROLL];
            #pragma unroll
            for (int k = 0; k < UNROLL; k++)
                v[k] = x4[base + k * BLOCK + tid];
            #pragma unroll
            for (int k = 0; k < UNROLL; k++) {
                vfloat4 ov;
                ov.x = eval(v[k].x);
                ov.y = eval(v[k].y);
                ov.z = eval(v[k].z);
                ov.w = eval(v[k].w);
                __builtin_nontemporal_store(ov, &o4[base + k * BLOCK + tid]);
            }
        } else {
            // Ragged last chunk.
            for (int i = base + tid; i < n4; i += BLOCK) {
                vfloat4 v = x4[i];
                vfloat4 ov;
                ov.x = eval(v.x);
                ov.y = eval(v.y);
                ov.z = eval(v.z);
                ov.w = eval(v.w);
                __builtin_nontemporal_store(ov, &o4[i]);
            }
        }
    }

    // Tail (n % 4 elements).
    const int rem  = n & 3;
    const int gtid = blockIdx.x * BLOCK + threadIdx.x;
    if (gtid < rem) {
        int i = (n4 << 2) + gtid;
        out[i] = eval(x[i]);
    }
}

extern "C" void kernel_launch(void* const* d_in, const int* in_sizes, int n_in,
                              void* d_out, int out_size, void* d_ws, size_t ws_size,
                              hipStream_t stream) {
    const float* x  = (const float*)d_in[0];
    const float* ns = (const float*)d_in[1];
    const float* a  = (const float*)d_in[2];
    float* out = (float*)d_out;
    const int n = in_sizes[0];
    const int H = in_sizes[1];

    const int chunk = BLOCK * UNROLL;
    int n4 = n >> 2;
    int grid = (n4 + chunk - 1) / chunk;       // 4096 blocks at n=32M
    if (grid < 1) grid = 1;
    if (grid > 16384) grid = 16384;
    size_t shmem = (size_t)H * 16;             // ns + a + float2 table
    adact_kernel<<<grid, BLOCK, shmem, stream>>>(x, ns, a, out, n, H);
}